// Round 28
// baseline (530.422 us; speedup 1.0000x reference)
//
#include <hip/hip_runtime.h>

#define NN 50000
#define N2 100000
#define EE 500000
#define E2 1000000

typedef unsigned short u16;
typedef unsigned int u32;

typedef __attribute__((ext_vector_type(8))) __bf16 bf16x8;
typedef __attribute__((ext_vector_type(4))) float f32x4;

__device__ __forceinline__ float4 ld4(const float* p) { return *(const float4*)p; }

// round-to-nearest-even f32 -> bf16 bits
__device__ __forceinline__ u16 f2bf(float f) {
  u32 u = __float_as_uint(f);
  u += 0x7FFFu + ((u >> 16) & 1u);
  return (u16)(u >> 16);
}

// w_r[k][h] (f32) ; wlB[h][k] bf16 padded to 16 rows (MFMA B-frag)
__global__ void L384_wred(const float* fc_w, const float* attn_l, const float* attn_r,
                          float* w_r, u16* wlB) {
  int k = threadIdx.x;
  for (int h = 0; h < 4; ++h) {
    float sl = 0.f, sr = 0.f;
    for (int d = 0; d < 64; ++d) {
      float f = fc_w[k * 256 + h * 64 + d];
      sl += f * attn_l[h * 64 + d];
      sr += f * attn_r[h * 64 + d];
    }
    w_r[k * 4 + h] = sr;
    wlB[h * 256 + k] = f2bf(sl);
  }
  for (int h = 4; h < 16; ++h) wlB[h * 256 + k] = 0;
}

// Bt[n][k] = bf16(fc_w[k][n])
__global__ void L384_bprep(const float* B, u16* Bt) {
  int n = blockIdx.x;
  int k = threadIdx.x;
  Bt[n * 256 + k] = f2bf(B[(size_t)k * 256 + n]);
}

// Wt[n][k] = bf16(Ww[k][n])
__global__ void L384_wprep(const float* Ww, u16* Wt) {
  int n = blockIdx.x;
  for (int k = threadIdx.x; k < 320; k += 256)
    Wt[(size_t)n * 320 + k] = f2bf(Ww[(size_t)k * 128 + n]);
}

// Abf[row][k] = bf16 of merged h_src (rows <NN user, else item)
__global__ void L384_aprep(const float* Au, const float* Ai, u16* Abf) {
  const int row = blockIdx.x * 4 + (threadIdx.x >> 6);
  const int lane = threadIdx.x & 63;
  if (row >= N2) return;
  const float* src = (row < NN) ? (Au + (size_t)row * 256)
                                : (Ai + (size_t)(row - NN) * 256);
  float4 v = ld4(src + lane * 4);
  u32 p01 = (u32)f2bf(v.x) | ((u32)f2bf(v.y) << 16);
  u32 p23 = (u32)f2bf(v.z) | ((u32)f2bf(v.w) << 16);
  *(uint2*)(Abf + (size_t)row * 256 + lane * 4) = make_uint2(p01, p23);
}

// merged xprep over 2NN rows
__global__ void L384_xprep(const float* hd_user, const float* hd_item,
                           const float* wr_, u16* X, float* er) {
  const int row = blockIdx.x * 4 + (threadIdx.x >> 6);
  const int lane = threadIdx.x & 63;
  if (row >= N2) return;
  const float* src = (row < NN) ? (hd_user + (size_t)row * 256)
                                : (hd_item + (size_t)(row - NN) * 256);
  float4 xv = ld4(src + lane * 4);
  u32 p01 = (u32)f2bf(xv.x) | ((u32)f2bf(xv.y) << 16);
  u32 p23 = (u32)f2bf(xv.z) | ((u32)f2bf(xv.w) << 16);
  *(uint2*)(X + (size_t)row * 320 + 64 + lane * 4) = make_uint2(p01, p23);
  const float* wr = wr_ + lane * 16;
  float4 w0 = ld4(wr), w1 = ld4(wr + 4), w2 = ld4(wr + 8), w3 = ld4(wr + 12);
  float a0 = xv.x * w0.x + xv.y * w1.x + xv.z * w2.x + xv.w * w3.x;
  float a1 = xv.x * w0.y + xv.y * w1.y + xv.z * w2.y + xv.w * w3.y;
  float a2 = xv.x * w0.z + xv.y * w1.z + xv.z * w2.z + xv.w * w3.z;
  float a3 = xv.x * w0.w + xv.y * w1.w + xv.z * w2.w + xv.w * w3.w;
  for (int off = 32; off; off >>= 1) {
    a0 += __shfl_xor(a0, off);
    a1 += __shfl_xor(a1, off);
    a2 += __shfl_xor(a2, off);
    a3 += __shfl_xor(a3, off);
  }
  if (lane == 0) {
    float* op = er + (size_t)row * 4;
    op[0] = a0; op[1] = a1; op[2] = a2; op[3] = a3;
  }
}

// merged gemm over Abf[2NN][256] bf16: fs = Abf @ fc_w, el = Abf @ w_l (wave 0).
// Block: 32 rows (2 rg x 16), 4 waves x 64-col strips; LDS-staged C-write.
__global__ void L384_gemm(const u16* Abf, const u16* Bt, const u16* wlB,
                          u16* C, float* el) {
  __shared__ u16 cs[32][264];
  const int t = threadIdx.x;
  const int w = t >> 6;
  const int l = t & 63;
  const int half = (blockIdx.x >= 1563) ? 1 : 0;
  const int base = half * NN;
  const int row0 = (blockIdx.x - half * 1563) * 32;
  const int lr = l & 15;
  const int kg = l >> 4;
  f32x4 acc[2][4];
  f32x4 eacc[2];
#pragma unroll
  for (int rg = 0; rg < 2; ++rg) {
    eacc[rg] = (f32x4){0.f, 0.f, 0.f, 0.f};
#pragma unroll
    for (int ct = 0; ct < 4; ++ct) acc[rg][ct] = (f32x4){0.f, 0.f, 0.f, 0.f};
  }
  const u16* arow[2];
#pragma unroll
  for (int rg = 0; rg < 2; ++rg) {
    int r = row0 + rg * 16 + lr;
    if (r >= NN) r = NN - 1;
    arow[rg] = Abf + (size_t)(base + r) * 256 + kg * 8;
  }
  const u16* bb = Bt + (size_t)(w * 64 + lr) * 256 + kg * 8;
  const u16* wl = wlB + lr * 256 + kg * 8;
#pragma unroll
  for (int k0 = 0; k0 < 256; k0 += 32) {
    union { bf16x8 v; uint4 q; } af[2], b[4], wf;
#pragma unroll
    for (int rg = 0; rg < 2; ++rg) af[rg].q = *(const uint4*)(arow[rg] + k0);
#pragma unroll
    for (int ct = 0; ct < 4; ++ct)
      b[ct].q = *(const uint4*)(bb + ct * 16 * 256 + k0);
    wf.q = *(const uint4*)(wl + k0);
#pragma unroll
    for (int rg = 0; rg < 2; ++rg) {
#pragma unroll
      for (int ct = 0; ct < 4; ++ct)
        acc[rg][ct] = __builtin_amdgcn_mfma_f32_16x16x32_bf16(af[rg].v, b[ct].v,
                                                              acc[rg][ct], 0, 0, 0);
      if (w == 0)
        eacc[rg] = __builtin_amdgcn_mfma_f32_16x16x32_bf16(af[rg].v, wf.v,
                                                           eacc[rg], 0, 0, 0);
    }
  }
#pragma unroll
  for (int rg = 0; rg < 2; ++rg)
#pragma unroll
    for (int ct = 0; ct < 4; ++ct)
#pragma unroll
      for (int r = 0; r < 4; ++r)
        cs[rg * 16 + kg * 4 + r][w * 64 + ct * 16 + lr] = f2bf(acc[rg][ct][r]);
#pragma unroll
  for (int rg = 0; rg < 2; ++rg) {
    if (w == 0 && lr < 4) {
#pragma unroll
      for (int r = 0; r < 4; ++r) {
        int grow = row0 + rg * 16 + kg * 4 + r;
        if (grow < NN) el[(size_t)(base + grow) * 4 + lr] = eacc[rg][r];
      }
    }
  }
  __syncthreads();
  const int row = t >> 3;
  const int c0 = (t & 7) * 32;
  const int grow = row0 + row;
  if (grow < NN) {
    const uint4* src = (const uint4*)&cs[row][c0];
    uint4* dst = (uint4*)(C + (size_t)(base + grow) * 256 + c0);
    dst[0] = src[0];
    dst[1] = src[1];
    dst[2] = src[2];
    dst[3] = src[3];
  }
}

__global__ void L384_zero(int* p, int n) {
  int i = blockIdx.x * 256 + threadIdx.x;
  if (i < n) p[i] = 0;
}
__global__ void L384_hist(const int* i2u_dst, const int* u2i_dst, int* cnt) {
  int e = blockIdx.x * 256 + threadIdx.x;
  if (e < EE) {
    int d = i2u_dst[e];
    d = ((unsigned)d < NN) ? d : 0;
    atomicAdd(&cnt[d], 1);
  } else if (e < E2) {
    int d = u2i_dst[e - EE];
    d = ((unsigned)d < NN) ? d : 0;
    atomicAdd(&cnt[NN + d], 1);
  }
}
__global__ void L384_scan1(const int* cnt, int* part, int* bsum, int n) {
  __shared__ int sh[256];
  const int t = threadIdx.x;
  const int base = blockIdx.x * 1024 + t * 4;
  int v0 = (base + 0 < n) ? cnt[base + 0] : 0;
  int v1 = (base + 1 < n) ? cnt[base + 1] : 0;
  int v2 = (base + 2 < n) ? cnt[base + 2] : 0;
  int v3 = (base + 3 < n) ? cnt[base + 3] : 0;
  int s0 = v0, s1 = s0 + v1, s2 = s1 + v2, s3 = s2 + v3;
  sh[t] = s3;
  __syncthreads();
  for (int off = 1; off < 256; off <<= 1) {
    int x = (t >= off) ? sh[t - off] : 0;
    __syncthreads();
    sh[t] += x;
    __syncthreads();
  }
  int excl = (t > 0) ? sh[t - 1] : 0;
  if (base + 0 < n) part[base + 0] = excl;
  if (base + 1 < n) part[base + 1] = excl + s0;
  if (base + 2 < n) part[base + 2] = excl + s1;
  if (base + 3 < n) part[base + 3] = excl + s2;
  if (t == 255) bsum[blockIdx.x] = sh[255];
}
__global__ void L384_scan2(int* bsum, int nb, int* indptr, int n) {
  if (threadIdx.x == 0 && blockIdx.x == 0) {
    int acc = 0;
    for (int i = 0; i < nb; ++i) {
      int c = bsum[i];
      bsum[i] = acc;
      acc += c;
    }
    indptr[n] = acc;
  }
}
__global__ void L384_scan3(int* indptr, const int* bsum, int* cur, int n) {
  int i = blockIdx.x * 256 + threadIdx.x;
  if (i < n) {
    int v = indptr[i] + bsum[i >> 10];
    indptr[i] = v;
    cur[i] = v;
  }
}
__global__ void L384_fill(const int* i2u_src, const int* i2u_dst,
                          const int* u2i_src, const int* u2i_dst,
                          int* cur, int* csr) {
  int e = blockIdx.x * 256 + threadIdx.x;
  if (e < EE) {
    int d = i2u_dst[e];
    d = ((unsigned)d < NN) ? d : 0;
    int s = i2u_src[e];
    s = ((unsigned)s < NN) ? s : 0;
    int pos = atomicAdd(&cur[d], 1);
    if ((unsigned)pos < E2) csr[pos] = NN + s;
  } else if (e < E2) {
    int d = u2i_dst[e - EE];
    d = ((unsigned)d < NN) ? d : 0;
    int s = u2i_src[e - EE];
    s = ((unsigned)s < NN) ? s : 0;
    int pos = atomicAdd(&cur[NN + d], 1);
    if ((unsigned)pos < E2) csr[pos] = s;
  }
}
__global__ void L384_sort(const int* indptr, int* csr, int n) {
  int i = blockIdx.x * 256 + threadIdx.x;
  if (i >= n) return;
  int p0 = indptr[i], p1 = indptr[i + 1];
  for (int a = p0 + 1; a < p1; ++a) {
    int v = csr[a];
    int b = a - 1;
    while (b >= p0 && csr[b] > v) {
      csr[b + 1] = csr[b];
      --b;
    }
    csr[b + 1] = v;
  }
}

// merged agg: single-pass softmax (no max shift; |e| small), x2 unrolled serial loop
__global__ void L384_agg(const int* indptr, const int* csr, const float* el,
                         const float* er, const u16* fs, const float* bias,
                         u16* X) {
  const int wid = blockIdx.x * 4 + (threadIdx.x >> 6);
  const int lane = threadIdx.x & 63;
  if (wid >= N2) return;
  const int p0 = indptr[wid];
  const int deg = indptr[wid + 1] - p0;
  const int h = lane >> 4;
  const int c = lane & 15;
  const float* erp = er + (size_t)wid * 4;
  float erh = erp[h];

  float den = 0.f;
  float ax = 0.f, ay = 0.f, az = 0.f, aw = 0.f;
  int i = 0;
  for (; i + 2 <= deg; i += 2) {
    int s0 = csr[p0 + i];
    int s1 = csr[p0 + i + 1];
    s0 = ((unsigned)s0 < N2) ? s0 : 0;
    s1 = ((unsigned)s1 < N2) ? s1 : 0;
    float e0 = el[(size_t)s0 * 4 + h] + erh;
    float e1 = el[(size_t)s1 * 4 + h] + erh;
    uint2 q0 = *(const uint2*)(fs + (size_t)s0 * 256 + lane * 4);
    uint2 q1 = *(const uint2*)(fs + (size_t)s1 * 256 + lane * 4);
    e0 = (e0 >= 0.f) ? e0 : 0.2f * e0;
    e1 = (e1 >= 0.f) ? e1 : 0.2f * e1;
    float ex0 = __expf(e0);
    float ex1 = __expf(e1);
    den += ex0;
    ax += ex0 * __uint_as_float(q0.x << 16);
    ay += ex0 * __uint_as_float(q0.x & 0xffff0000u);
    az += ex0 * __uint_as_float(q0.y << 16);
    aw += ex0 * __uint_as_float(q0.y & 0xffff0000u);
    den += ex1;
    ax += ex1 * __uint_as_float(q1.x << 16);
    ay += ex1 * __uint_as_float(q1.x & 0xffff0000u);
    az += ex1 * __uint_as_float(q1.y << 16);
    aw += ex1 * __uint_as_float(q1.y & 0xffff0000u);
  }
  if (i < deg) {
    int s0 = csr[p0 + i];
    s0 = ((unsigned)s0 < N2) ? s0 : 0;
    float e0 = el[(size_t)s0 * 4 + h] + erh;
    uint2 q0 = *(const uint2*)(fs + (size_t)s0 * 256 + lane * 4);
    e0 = (e0 >= 0.f) ? e0 : 0.2f * e0;
    float ex0 = __expf(e0);
    den += ex0;
    ax += ex0 * __uint_as_float(q0.x << 16);
    ay += ex0 * __uint_as_float(q0.x & 0xffff0000u);
    az += ex0 * __uint_as_float(q0.y << 16);
    aw += ex0 * __uint_as_float(q0.y & 0xffff0000u);
  }
  const float* bp = bias + lane * 4;
  float inv = (deg > 0) ? 1.f / den : 0.f;
  float ox = ax * inv + bp[0];
  float oy = ay * inv + bp[1];
  float oz = az * inv + bp[2];
  float ow = aw * inv + bp[3];
  for (int off = 16; off <= 32; off <<= 1) {
    ox += __shfl_xor(ox, off);
    oy += __shfl_xor(oy, off);
    oz += __shfl_xor(oz, off);
    ow += __shfl_xor(ow, off);
  }
  if (h == 0) {
    u32 p01 = (u32)f2bf(ox * 0.25f) | ((u32)f2bf(oy * 0.25f) << 16);
    u32 p23 = (u32)f2bf(oz * 0.25f) | ((u32)f2bf(ow * 0.25f) << 16);
    *(uint2*)(X + (size_t)wid * 320 + 4 * c) = make_uint2(p01, p23);
  }
}

// head via MFMA over merged X[2NN][320]; out rows = [z_user; z_item]
__global__ void L384_headm(const u16* X, const u16* Wt, const float* Wb, float* out) {
  __shared__ float red[4][16];
  const int t = threadIdx.x;
  const int w = t >> 6;
  const int l = t & 63;
  const int row0 = blockIdx.x * 16;
  const int lr = l & 15;
  const int kg = l >> 4;
  f32x4 acc0 = {0.f, 0.f, 0.f, 0.f};
  f32x4 acc1 = {0.f, 0.f, 0.f, 0.f};
  const u16* arow = X + (size_t)(row0 + lr) * 320 + kg * 8;
  const u16* b0row = Wt + (size_t)(w * 32 + lr) * 320 + kg * 8;
  const u16* b1row = Wt + (size_t)(w * 32 + 16 + lr) * 320 + kg * 8;
#pragma unroll
  for (int k0 = 0; k0 < 320; k0 += 32) {
    union { bf16x8 v; uint4 q; } af, b0, b1;
    af.q = *(const uint4*)(arow + k0);
    b0.q = *(const uint4*)(b0row + k0);
    b1.q = *(const uint4*)(b1row + k0);
    acc0 = __builtin_amdgcn_mfma_f32_16x16x32_bf16(af.v, b0.v, acc0, 0, 0, 0);
    acc1 = __builtin_amdgcn_mfma_f32_16x16x32_bf16(af.v, b1.v, acc1, 0, 0, 0);
  }
  const int col0 = w * 32 + lr;
  const int col1 = col0 + 16;
  float wb0 = Wb[col0], wb1 = Wb[col1];
  float z0[4], z1[4], pssq[4];
#pragma unroll
  for (int r = 0; r < 4; ++r) {
    z0[r] = fmaxf(acc0[r] + wb0, 0.f);
    z1[r] = fmaxf(acc1[r] + wb1, 0.f);
    pssq[r] = z0[r] * z0[r] + z1[r] * z1[r];
  }
#pragma unroll
  for (int off = 8; off; off >>= 1) {
#pragma unroll
    for (int r = 0; r < 4; ++r) pssq[r] += __shfl_xor(pssq[r], off);
  }
  if (lr == 0) {
#pragma unroll
    for (int r = 0; r < 4; ++r) red[w][kg * 4 + r] = pssq[r];
  }
  __syncthreads();
#pragma unroll
  for (int r = 0; r < 4; ++r) {
    int row = kg * 4 + r;
    float ssq = red[0][row] + red[1][row] + red[2][row] + red[3][row];
    float inv = (ssq > 0.f) ? rsqrtf(ssq) : 0.f;
    float* op = out + (size_t)(row0 + row) * 128;
    op[col0] = z0[r] * inv;
    op[col1] = z1[r] * inv;
  }
}

extern "C" void kernel_launch(void* const* d_in, const int* in_sizes, int n_in,
                              void* d_out, int out_size, void* d_ws, size_t ws_size,
                              hipStream_t stream) {
  (void)in_sizes; (void)n_in; (void)out_size; (void)ws_size;
  const float* h_src_user = (const float*)d_in[0];
  const float* h_src_item = (const float*)d_in[1];
  const float* h_dst_user = (const float*)d_in[2];
  const float* h_dst_item = (const float*)d_in[3];
  const int* u2i_src = (const int*)d_in[4];
  const int* u2i_dst = (const int*)d_in[5];
  const int* i2u_src = (const int*)d_in[6];
  const int* i2u_dst = (const int*)d_in[7];
  const float* fc_w = (const float*)d_in[8];
  const float* attn_l = (const float*)d_in[9];
  const float* attn_r = (const float*)d_in[10];
  const float* gat_bias = (const float*)d_in[11];
  const float* W_w = (const float*)d_in[12];
  const float* W_b = (const float*)d_in[13];
  float* out = (float*)d_out;  // f32 [2NN][128] = [z_user; z_item]

  float* el = (float*)d_ws;                     // N2*4
  float* er = el + (size_t)N2 * 4;              // N2*4
  float* w_r = er + (size_t)N2 * 4;             // 1024
  u16* wlB = (u16*)(w_r + 1024);                // 16*256
  u16* fs = wlB + 16 * 256;                     // N2*256 bf16
  u16* X = fs + (size_t)N2 * 256;               // N2*320 bf16
  u16* Abf = X + (size_t)N2 * 320;              // N2*256 bf16 (src features)
  u16* Bt = Abf + (size_t)N2 * 256;             // 256*256
  u16* Wt = Bt + 256 * 256;                     // 128*320
  int* indptr = (int*)(Wt + 128 * 320);         // N2+1 (+pad)
  int* cur = indptr + (N2 + 4);                 // N2
  int* csr = cur + N2;                          // E2
  int* bsum = csr + E2;                         // 128

  // shared precompute
  L384_wred<<<1, 256, 0, stream>>>(fc_w, attn_l, attn_r, w_r, wlB);
  L384_bprep<<<256, 256, 0, stream>>>(fc_w, Bt);
  L384_wprep<<<128, 256, 0, stream>>>(W_w, Wt);
  L384_aprep<<<25000, 256, 0, stream>>>(h_src_user, h_src_item, Abf);
  L384_xprep<<<25000, 256, 0, stream>>>(h_dst_user, h_dst_item, w_r, X, er);

  // merged CSR build (2NN nodes, 2EE edges)
  L384_zero<<<391, 256, 0, stream>>>(cur, N2);
  L384_hist<<<3907, 256, 0, stream>>>(i2u_dst, u2i_dst, cur);
  L384_scan1<<<98, 256, 0, stream>>>(cur, indptr, bsum, N2);
  L384_scan2<<<1, 1, 0, stream>>>(bsum, 98, indptr, N2);
  L384_scan3<<<391, 256, 0, stream>>>(indptr, bsum, cur, N2);
  L384_fill<<<3907, 256, 0, stream>>>(i2u_src, i2u_dst, u2i_src, u2i_dst, cur, csr);
  L384_sort<<<391, 256, 0, stream>>>(indptr, csr, N2);

  // merged compute
  L384_gemm<<<3126, 256, 0, stream>>>(Abf, Bt, wlB, fs, el);
  L384_agg<<<25000, 256, 0, stream>>>(indptr, csr, el, er, fs, gat_bias, X);
  L384_headm<<<6250, 256, 0, stream>>>(X, Wt, W_b, out);
}

// Round 29
// 528.913 us; speedup vs baseline: 1.0029x; 1.0029x over previous
//
#include <hip/hip_runtime.h>

#define NN 50000
#define N2 100000
#define EE 500000
#define E2 1000000

typedef unsigned short u16;
typedef unsigned int u32;

typedef __attribute__((ext_vector_type(8))) __bf16 bf16x8;
typedef __attribute__((ext_vector_type(4))) float f32x4;

__device__ __forceinline__ float4 ld4(const float* p) { return *(const float4*)p; }

// round-to-nearest-even f32 -> bf16 bits
__device__ __forceinline__ u16 f2bf(float f) {
  u32 u = __float_as_uint(f);
  u += 0x7FFFu + ((u >> 16) & 1u);
  return (u16)(u >> 16);
}

// w_l[k][h], w_r[k][h] (f32)
__global__ void L384_wred(const float* fc_w, const float* attn_l, const float* attn_r,
                          float* w_l, float* w_r) {
  int k = threadIdx.x;
  for (int h = 0; h < 4; ++h) {
    float sl = 0.f, sr = 0.f;
    for (int d = 0; d < 64; ++d) {
      float f = fc_w[k * 256 + h * 64 + d];
      sl += f * attn_l[h * 64 + d];
      sr += f * attn_r[h * 64 + d];
    }
    w_l[k * 4 + h] = sl;
    w_r[k * 4 + h] = sr;
  }
}

// Bt[n][k] = bf16(fc_w[k][n])
__global__ void L384_bprep(const float* B, u16* Bt) {
  int n = blockIdx.x;
  int k = threadIdx.x;
  Bt[n * 256 + k] = f2bf(B[(size_t)k * 256 + n]);
}

// Wt[n][k] = bf16(Ww[k][n])
__global__ void L384_wprep(const float* Ww, u16* Wt) {
  int n = blockIdx.x;
  for (int k = threadIdx.x; k < 320; k += 256)
    Wt[(size_t)n * 320 + k] = f2bf(Ww[(size_t)k * 128 + n]);
}

// merged prep over 4NN rows:
//  rid <  N2: src features -> Abf[rid] (bf16) and el[rid] = src . w_l (f32)
//  rid >= N2: dst features -> X[r][64..320) (bf16) and er[r] = dst . w_r (f32)
__global__ void L384_prep(const float* Au, const float* Ai, const float* Du,
                          const float* Di, const float* w_l, const float* w_r,
                          u16* Abf, u16* X, float* el, float* er) {
  const int rid = blockIdx.x * 4 + (threadIdx.x >> 6);
  const int lane = threadIdx.x & 63;
  const int isA = (rid < N2) ? 1 : 0;
  const int r = isA ? rid : rid - N2;
  const float* src = isA ? ((r < NN) ? Au + (size_t)r * 256 : Ai + (size_t)(r - NN) * 256)
                         : ((r < NN) ? Du + (size_t)r * 256 : Di + (size_t)(r - NN) * 256);
  float4 xv = ld4(src + lane * 4);
  u32 p01 = (u32)f2bf(xv.x) | ((u32)f2bf(xv.y) << 16);
  u32 p23 = (u32)f2bf(xv.z) | ((u32)f2bf(xv.w) << 16);
  if (isA)
    *(uint2*)(Abf + (size_t)r * 256 + lane * 4) = make_uint2(p01, p23);
  else
    *(uint2*)(X + (size_t)r * 320 + 64 + lane * 4) = make_uint2(p01, p23);
  const float* wsel = isA ? w_l : w_r;
  const float* wr = wsel + lane * 16;
  float4 w0 = ld4(wr), w1 = ld4(wr + 4), w2 = ld4(wr + 8), w3 = ld4(wr + 12);
  float a0 = xv.x * w0.x + xv.y * w1.x + xv.z * w2.x + xv.w * w3.x;
  float a1 = xv.x * w0.y + xv.y * w1.y + xv.z * w2.y + xv.w * w3.y;
  float a2 = xv.x * w0.z + xv.y * w1.z + xv.z * w2.z + xv.w * w3.z;
  float a3 = xv.x * w0.w + xv.y * w1.w + xv.z * w2.w + xv.w * w3.w;
  for (int off = 32; off; off >>= 1) {
    a0 += __shfl_xor(a0, off);
    a1 += __shfl_xor(a1, off);
    a2 += __shfl_xor(a2, off);
    a3 += __shfl_xor(a3, off);
  }
  if (lane == 0) {
    float* op = (isA ? el : er) + (size_t)r * 4;
    op[0] = a0; op[1] = a1; op[2] = a2; op[3] = a3;
  }
}

// merged gemm: fs = Abf @ fc_w. 512 threads / 64 rows per block.
// Wave w: rows (w>>2)*32 .. +31 (2 rg), col strip (w&3)*64 (4 tiles).
__global__ __launch_bounds__(512) void L384_gemm(const u16* Abf, const u16* Bt,
                                                 u16* C) {
  __shared__ u16 cs[64][264];
  const int t = threadIdx.x;
  const int w = t >> 6;
  const int l = t & 63;
  const int half = (blockIdx.x >= 782) ? 1 : 0;
  const int base = half * NN;
  const int brow0 = (blockIdx.x - half * 782) * 64;
  const int row0 = brow0 + (w >> 2) * 32;
  const int cw = w & 3;
  const int lr = l & 15;
  const int kg = l >> 4;
  f32x4 acc[2][4];
#pragma unroll
  for (int rg = 0; rg < 2; ++rg)
#pragma unroll
    for (int ct = 0; ct < 4; ++ct) acc[rg][ct] = (f32x4){0.f, 0.f, 0.f, 0.f};
  const u16* arow[2];
#pragma unroll
  for (int rg = 0; rg < 2; ++rg) {
    int r = row0 + rg * 16 + lr;
    if (r >= NN) r = NN - 1;
    arow[rg] = Abf + (size_t)(base + r) * 256 + kg * 8;
  }
  const u16* bb = Bt + (size_t)(cw * 64 + lr) * 256 + kg * 8;
#pragma unroll
  for (int k0 = 0; k0 < 256; k0 += 32) {
    union { bf16x8 v; uint4 q; } af[2], b[4];
#pragma unroll
    for (int rg = 0; rg < 2; ++rg) af[rg].q = *(const uint4*)(arow[rg] + k0);
#pragma unroll
    for (int ct = 0; ct < 4; ++ct)
      b[ct].q = *(const uint4*)(bb + ct * 16 * 256 + k0);
#pragma unroll
    for (int rg = 0; rg < 2; ++rg)
#pragma unroll
      for (int ct = 0; ct < 4; ++ct)
        acc[rg][ct] = __builtin_amdgcn_mfma_f32_16x16x32_bf16(af[rg].v, b[ct].v,
                                                              acc[rg][ct], 0, 0, 0);
  }
#pragma unroll
  for (int rg = 0; rg < 2; ++rg)
#pragma unroll
    for (int ct = 0; ct < 4; ++ct)
#pragma unroll
      for (int r = 0; r < 4; ++r)
        cs[(w >> 2) * 32 + rg * 16 + kg * 4 + r][cw * 64 + ct * 16 + lr] =
            f2bf(acc[rg][ct][r]);
  __syncthreads();
  const int row = t >> 3;
  const int c0 = (t & 7) * 32;
  const int grow = brow0 + row;
  if (grow < NN) {
    const uint4* src = (const uint4*)&cs[row][c0];
    uint4* dst = (uint4*)(C + (size_t)(base + grow) * 256 + c0);
    dst[0] = src[0];
    dst[1] = src[1];
    dst[2] = src[2];
    dst[3] = src[3];
  }
}

__global__ void L384_zero(int* p, int n) {
  int i = blockIdx.x * 256 + threadIdx.x;
  if (i < n) p[i] = 0;
}
__global__ void L384_hist(const int* i2u_dst, const int* u2i_dst, int* cnt) {
  int e = blockIdx.x * 256 + threadIdx.x;
  if (e < EE) {
    int d = i2u_dst[e];
    d = ((unsigned)d < NN) ? d : 0;
    atomicAdd(&cnt[d], 1);
  } else if (e < E2) {
    int d = u2i_dst[e - EE];
    d = ((unsigned)d < NN) ? d : 0;
    atomicAdd(&cnt[NN + d], 1);
  }
}
__global__ void L384_scan1(const int* cnt, int* part, int* bsum, int n) {
  __shared__ int sh[256];
  const int t = threadIdx.x;
  const int base = blockIdx.x * 1024 + t * 4;
  int v0 = (base + 0 < n) ? cnt[base + 0] : 0;
  int v1 = (base + 1 < n) ? cnt[base + 1] : 0;
  int v2 = (base + 2 < n) ? cnt[base + 2] : 0;
  int v3 = (base + 3 < n) ? cnt[base + 3] : 0;
  int s0 = v0, s1 = s0 + v1, s2 = s1 + v2, s3 = s2 + v3;
  sh[t] = s3;
  __syncthreads();
  for (int off = 1; off < 256; off <<= 1) {
    int x = (t >= off) ? sh[t - off] : 0;
    __syncthreads();
    sh[t] += x;
    __syncthreads();
  }
  int excl = (t > 0) ? sh[t - 1] : 0;
  if (base + 0 < n) part[base + 0] = excl;
  if (base + 1 < n) part[base + 1] = excl + s0;
  if (base + 2 < n) part[base + 2] = excl + s1;
  if (base + 3 < n) part[base + 3] = excl + s2;
  if (t == 255) bsum[blockIdx.x] = sh[255];
}
__global__ void L384_scan2(int* bsum, int nb, int* indptr, int n) {
  if (threadIdx.x == 0 && blockIdx.x == 0) {
    int acc = 0;
    for (int i = 0; i < nb; ++i) {
      int c = bsum[i];
      bsum[i] = acc;
      acc += c;
    }
    indptr[n] = acc;
  }
}
__global__ void L384_scan3(int* indptr, const int* bsum, int* cur, int n) {
  int i = blockIdx.x * 256 + threadIdx.x;
  if (i < n) {
    int v = indptr[i] + bsum[i >> 10];
    indptr[i] = v;
    cur[i] = v;
  }
}
__global__ void L384_fill(const int* i2u_src, const int* i2u_dst,
                          const int* u2i_src, const int* u2i_dst,
                          int* cur, int* csr) {
  int e = blockIdx.x * 256 + threadIdx.x;
  if (e < EE) {
    int d = i2u_dst[e];
    d = ((unsigned)d < NN) ? d : 0;
    int s = i2u_src[e];
    s = ((unsigned)s < NN) ? s : 0;
    int pos = atomicAdd(&cur[d], 1);
    if ((unsigned)pos < E2) csr[pos] = NN + s;
  } else if (e < E2) {
    int d = u2i_dst[e - EE];
    d = ((unsigned)d < NN) ? d : 0;
    int s = u2i_src[e - EE];
    s = ((unsigned)s < NN) ? s : 0;
    int pos = atomicAdd(&cur[NN + d], 1);
    if ((unsigned)pos < E2) csr[pos] = s;
  }
}
__global__ void L384_sort(const int* indptr, int* csr, int n) {
  int i = blockIdx.x * 256 + threadIdx.x;
  if (i >= n) return;
  int p0 = indptr[i], p1 = indptr[i + 1];
  for (int a = p0 + 1; a < p1; ++a) {
    int v = csr[a];
    int b = a - 1;
    while (b >= p0 && csr[b] > v) {
      csr[b + 1] = csr[b];
      --b;
    }
    csr[b + 1] = v;
  }
}

// merged agg: single-pass softmax, x2 unrolled serial loop (deterministic)
__global__ void L384_agg(const int* indptr, const int* csr, const float* el,
                         const float* er, const u16* fs, const float* bias,
                         u16* X) {
  const int wid = blockIdx.x * 4 + (threadIdx.x >> 6);
  const int lane = threadIdx.x & 63;
  if (wid >= N2) return;
  const int p0 = indptr[wid];
  const int deg = indptr[wid + 1] - p0;
  const int h = lane >> 4;
  const int c = lane & 15;
  const float* erp = er + (size_t)wid * 4;
  float erh = erp[h];

  float den = 0.f;
  float ax = 0.f, ay = 0.f, az = 0.f, aw = 0.f;
  int i = 0;
  for (; i + 2 <= deg; i += 2) {
    int s0 = csr[p0 + i];
    int s1 = csr[p0 + i + 1];
    s0 = ((unsigned)s0 < N2) ? s0 : 0;
    s1 = ((unsigned)s1 < N2) ? s1 : 0;
    float e0 = el[(size_t)s0 * 4 + h] + erh;
    float e1 = el[(size_t)s1 * 4 + h] + erh;
    uint2 q0 = *(const uint2*)(fs + (size_t)s0 * 256 + lane * 4);
    uint2 q1 = *(const uint2*)(fs + (size_t)s1 * 256 + lane * 4);
    e0 = (e0 >= 0.f) ? e0 : 0.2f * e0;
    e1 = (e1 >= 0.f) ? e1 : 0.2f * e1;
    float ex0 = __expf(e0);
    float ex1 = __expf(e1);
    den += ex0;
    ax += ex0 * __uint_as_float(q0.x << 16);
    ay += ex0 * __uint_as_float(q0.x & 0xffff0000u);
    az += ex0 * __uint_as_float(q0.y << 16);
    aw += ex0 * __uint_as_float(q0.y & 0xffff0000u);
    den += ex1;
    ax += ex1 * __uint_as_float(q1.x << 16);
    ay += ex1 * __uint_as_float(q1.x & 0xffff0000u);
    az += ex1 * __uint_as_float(q1.y << 16);
    aw += ex1 * __uint_as_float(q1.y & 0xffff0000u);
  }
  if (i < deg) {
    int s0 = csr[p0 + i];
    s0 = ((unsigned)s0 < N2) ? s0 : 0;
    float e0 = el[(size_t)s0 * 4 + h] + erh;
    uint2 q0 = *(const uint2*)(fs + (size_t)s0 * 256 + lane * 4);
    e0 = (e0 >= 0.f) ? e0 : 0.2f * e0;
    float ex0 = __expf(e0);
    den += ex0;
    ax += ex0 * __uint_as_float(q0.x << 16);
    ay += ex0 * __uint_as_float(q0.x & 0xffff0000u);
    az += ex0 * __uint_as_float(q0.y << 16);
    aw += ex0 * __uint_as_float(q0.y & 0xffff0000u);
  }
  const float* bp = bias + lane * 4;
  float inv = (deg > 0) ? 1.f / den : 0.f;
  float ox = ax * inv + bp[0];
  float oy = ay * inv + bp[1];
  float oz = az * inv + bp[2];
  float ow = aw * inv + bp[3];
  for (int off = 16; off <= 32; off <<= 1) {
    ox += __shfl_xor(ox, off);
    oy += __shfl_xor(oy, off);
    oz += __shfl_xor(oz, off);
    ow += __shfl_xor(ow, off);
  }
  if (h == 0) {
    u32 p01 = (u32)f2bf(ox * 0.25f) | ((u32)f2bf(oy * 0.25f) << 16);
    u32 p23 = (u32)f2bf(oz * 0.25f) | ((u32)f2bf(ow * 0.25f) << 16);
    *(uint2*)(X + (size_t)wid * 320 + 4 * c) = make_uint2(p01, p23);
  }
}

// head via MFMA over merged X[2NN][320]; out rows = [z_user; z_item]
__global__ void L384_headm(const u16* X, const u16* Wt, const float* Wb, float* out) {
  __shared__ float red[4][16];
  const int t = threadIdx.x;
  const int w = t >> 6;
  const int l = t & 63;
  const int row0 = blockIdx.x * 16;
  const int lr = l & 15;
  const int kg = l >> 4;
  f32x4 acc0 = {0.f, 0.f, 0.f, 0.f};
  f32x4 acc1 = {0.f, 0.f, 0.f, 0.f};
  const u16* arow = X + (size_t)(row0 + lr) * 320 + kg * 8;
  const u16* b0row = Wt + (size_t)(w * 32 + lr) * 320 + kg * 8;
  const u16* b1row = Wt + (size_t)(w * 32 + 16 + lr) * 320 + kg * 8;
#pragma unroll
  for (int k0 = 0; k0 < 320; k0 += 32) {
    union { bf16x8 v; uint4 q; } af, b0, b1;
    af.q = *(const uint4*)(arow + k0);
    b0.q = *(const uint4*)(b0row + k0);
    b1.q = *(const uint4*)(b1row + k0);
    acc0 = __builtin_amdgcn_mfma_f32_16x16x32_bf16(af.v, b0.v, acc0, 0, 0, 0);
    acc1 = __builtin_amdgcn_mfma_f32_16x16x32_bf16(af.v, b1.v, acc1, 0, 0, 0);
  }
  const int col0 = w * 32 + lr;
  const int col1 = col0 + 16;
  float wb0 = Wb[col0], wb1 = Wb[col1];
  float z0[4], z1[4], pssq[4];
#pragma unroll
  for (int r = 0; r < 4; ++r) {
    z0[r] = fmaxf(acc0[r] + wb0, 0.f);
    z1[r] = fmaxf(acc1[r] + wb1, 0.f);
    pssq[r] = z0[r] * z0[r] + z1[r] * z1[r];
  }
#pragma unroll
  for (int off = 8; off; off >>= 1) {
#pragma unroll
    for (int r = 0; r < 4; ++r) pssq[r] += __shfl_xor(pssq[r], off);
  }
  if (lr == 0) {
#pragma unroll
    for (int r = 0; r < 4; ++r) red[w][kg * 4 + r] = pssq[r];
  }
  __syncthreads();
#pragma unroll
  for (int r = 0; r < 4; ++r) {
    int row = kg * 4 + r;
    float ssq = red[0][row] + red[1][row] + red[2][row] + red[3][row];
    float inv = (ssq > 0.f) ? rsqrtf(ssq) : 0.f;
    float* op = out + (size_t)(row0 + row) * 128;
    op[col0] = z0[r] * inv;
    op[col1] = z1[r] * inv;
  }
}

extern "C" void kernel_launch(void* const* d_in, const int* in_sizes, int n_in,
                              void* d_out, int out_size, void* d_ws, size_t ws_size,
                              hipStream_t stream) {
  (void)in_sizes; (void)n_in; (void)out_size; (void)ws_size;
  const float* h_src_user = (const float*)d_in[0];
  const float* h_src_item = (const float*)d_in[1];
  const float* h_dst_user = (const float*)d_in[2];
  const float* h_dst_item = (const float*)d_in[3];
  const int* u2i_src = (const int*)d_in[4];
  const int* u2i_dst = (const int*)d_in[5];
  const int* i2u_src = (const int*)d_in[6];
  const int* i2u_dst = (const int*)d_in[7];
  const float* fc_w = (const float*)d_in[8];
  const float* attn_l = (const float*)d_in[9];
  const float* attn_r = (const float*)d_in[10];
  const float* gat_bias = (const float*)d_in[11];
  const float* W_w = (const float*)d_in[12];
  const float* W_b = (const float*)d_in[13];
  float* out = (float*)d_out;  // f32 [2NN][128] = [z_user; z_item]

  float* el = (float*)d_ws;                     // N2*4
  float* er = el + (size_t)N2 * 4;              // N2*4
  float* w_l = er + (size_t)N2 * 4;             // 1024
  float* w_r = w_l + 1024;                      // 1024
  u16* fs = (u16*)(w_r + 1024);                 // N2*256 bf16
  u16* X = fs + (size_t)N2 * 256;               // N2*320 bf16
  u16* Abf = X + (size_t)N2 * 320;              // N2*256 bf16
  u16* Bt = Abf + (size_t)N2 * 256;             // 256*256
  u16* Wt = Bt + 256 * 256;                     // 128*320
  int* indptr = (int*)(Wt + 128 * 320);         // N2+1 (+pad)
  int* cur = indptr + (N2 + 4);                 // N2
  int* csr = cur + N2;                          // E2
  int* bsum = csr + E2;                         // 128

  // shared precompute
  L384_wred<<<1, 256, 0, stream>>>(fc_w, attn_l, attn_r, w_l, w_r);
  L384_bprep<<<256, 256, 0, stream>>>(fc_w, Bt);
  L384_wprep<<<128, 256, 0, stream>>>(W_w, Wt);
  L384_prep<<<50000, 256, 0, stream>>>(h_src_user, h_src_item, h_dst_user,
                                       h_dst_item, w_l, w_r, Abf, X, el, er);

  // merged CSR build (2NN nodes, 2EE edges)
  L384_zero<<<391, 256, 0, stream>>>(cur, N2);
  L384_hist<<<3907, 256, 0, stream>>>(i2u_dst, u2i_dst, cur);
  L384_scan1<<<98, 256, 0, stream>>>(cur, indptr, bsum, N2);
  L384_scan2<<<1, 1, 0, stream>>>(bsum, 98, indptr, N2);
  L384_scan3<<<391, 256, 0, stream>>>(indptr, bsum, cur, N2);
  L384_fill<<<3907, 256, 0, stream>>>(i2u_src, i2u_dst, u2i_src, u2i_dst, cur, csr);
  L384_sort<<<391, 256, 0, stream>>>(indptr, csr, N2);

  // merged compute
  L384_gemm<<<1564, 512, 0, stream>>>(Abf, Bt, fs);
  L384_agg<<<25000, 256, 0, stream>>>(indptr, csr, el, er, fs, gat_bias, X);
  L384_headm<<<6250, 256, 0, stream>>>(X, Wt, W_b, out);
}

// Round 30
// 480.709 us; speedup vs baseline: 1.1034x; 1.1003x over previous
//
#include <hip/hip_runtime.h>

#define NN 50000
#define N2 100000
#define EE 500000
#define E2 1000000

typedef unsigned short u16;
typedef unsigned int u32;

typedef __attribute__((ext_vector_type(8))) __bf16 bf16x8;
typedef __attribute__((ext_vector_type(4))) float f32x4;

__device__ __forceinline__ float4 ld4(const float* p) { return *(const float4*)p; }

// round-to-nearest-even f32 -> bf16 bits
__device__ __forceinline__ u16 f2bf(float f) {
  u32 u = __float_as_uint(f);
  u += 0x7FFFu + ((u >> 16) & 1u);
  return (u16)(u >> 16);
}

// w_l[k][h], w_r[k][h] (f32)
__global__ void L384_wred(const float* fc_w, const float* attn_l, const float* attn_r,
                          float* w_l, float* w_r) {
  int k = threadIdx.x;
  for (int h = 0; h < 4; ++h) {
    float sl = 0.f, sr = 0.f;
    for (int d = 0; d < 64; ++d) {
      float f = fc_w[k * 256 + h * 64 + d];
      sl += f * attn_l[h * 64 + d];
      sr += f * attn_r[h * 64 + d];
    }
    w_l[k * 4 + h] = sl;
    w_r[k * 4 + h] = sr;
  }
}

// Bt[n][k] = bf16(fc_w[k][n])
__global__ void L384_bprep(const float* B, u16* Bt) {
  int n = blockIdx.x;
  int k = threadIdx.x;
  Bt[n * 256 + k] = f2bf(B[(size_t)k * 256 + n]);
}

// Wt[n][k] = bf16(Ww[k][n])
__global__ void L384_wprep(const float* Ww, u16* Wt) {
  int n = blockIdx.x;
  for (int k = threadIdx.x; k < 320; k += 256)
    Wt[(size_t)n * 320 + k] = f2bf(Ww[(size_t)k * 128 + n]);
}

// merged prep over 4NN rows:
//  rid <  N2: src features -> Abf[rid] (bf16) and el[rid] = src . w_l (f32)
//  rid >= N2: dst features -> X[r][64..320) (bf16) and er[r] = dst . w_r (f32)
__global__ void L384_prep(const float* Au, const float* Ai, const float* Du,
                          const float* Di, const float* w_l, const float* w_r,
                          u16* Abf, u16* X, float* el, float* er) {
  const int rid = blockIdx.x * 4 + (threadIdx.x >> 6);
  const int lane = threadIdx.x & 63;
  const int isA = (rid < N2) ? 1 : 0;
  const int r = isA ? rid : rid - N2;
  const float* src = isA ? ((r < NN) ? Au + (size_t)r * 256 : Ai + (size_t)(r - NN) * 256)
                         : ((r < NN) ? Du + (size_t)r * 256 : Di + (size_t)(r - NN) * 256);
  float4 xv = ld4(src + lane * 4);
  u32 p01 = (u32)f2bf(xv.x) | ((u32)f2bf(xv.y) << 16);
  u32 p23 = (u32)f2bf(xv.z) | ((u32)f2bf(xv.w) << 16);
  if (isA)
    *(uint2*)(Abf + (size_t)r * 256 + lane * 4) = make_uint2(p01, p23);
  else
    *(uint2*)(X + (size_t)r * 320 + 64 + lane * 4) = make_uint2(p01, p23);
  const float* wsel = isA ? w_l : w_r;
  const float* wr = wsel + lane * 16;
  float4 w0 = ld4(wr), w1 = ld4(wr + 4), w2 = ld4(wr + 8), w3 = ld4(wr + 12);
  float a0 = xv.x * w0.x + xv.y * w1.x + xv.z * w2.x + xv.w * w3.x;
  float a1 = xv.x * w0.y + xv.y * w1.y + xv.z * w2.y + xv.w * w3.y;
  float a2 = xv.x * w0.z + xv.y * w1.z + xv.z * w2.z + xv.w * w3.z;
  float a3 = xv.x * w0.w + xv.y * w1.w + xv.z * w2.w + xv.w * w3.w;
  for (int off = 32; off; off >>= 1) {
    a0 += __shfl_xor(a0, off);
    a1 += __shfl_xor(a1, off);
    a2 += __shfl_xor(a2, off);
    a3 += __shfl_xor(a3, off);
  }
  if (lane == 0) {
    float* op = (isA ? el : er) + (size_t)r * 4;
    op[0] = a0; op[1] = a1; op[2] = a2; op[3] = a3;
  }
}

// gemm: fs = Abf @ fc_w over merged rows. Block = 128 rows x 64-col strip,
// 8 waves x 16 rows. B-strip staged in LDS once; all 8 A-fragments preloaded.
// Grid: 782 row-blocks x 4 strips (strip = blockIdx & 3).
__global__ __launch_bounds__(512) void L384_gemm(const u16* Abf, const u16* Bt,
                                                 u16* C) {
  __shared__ u16 bs[64][264];  // B strip (and C staging after the loop)
  const int t = threadIdx.x;
  const int w = t >> 6;
  const int l = t & 63;
  const int lr = l & 15;
  const int kg = l >> 4;
  const int strip = blockIdx.x & 3;
  const int rb = blockIdx.x >> 2;
  const int row0 = rb * 128;

  // preload all 8 A-fragments (independent global loads, max MLP)
  const int row = row0 + w * 16 + lr;
  const int rr = (row < N2) ? row : (N2 - 1);
  const u16* arow = Abf + (size_t)rr * 256 + kg * 8;
  uint4 a[8];
#pragma unroll
  for (int ks = 0; ks < 8; ++ks) a[ks] = *(const uint4*)(arow + ks * 32);

  // stage B strip: 64 rows x 512B
  {
    const int brow = t >> 3;
    const int bc = (t & 7) * 32;
    const uint4* s = (const uint4*)(Bt + (size_t)(strip * 64 + brow) * 256 + bc);
    uint4* d = (uint4*)&bs[brow][bc];
    d[0] = s[0]; d[1] = s[1]; d[2] = s[2]; d[3] = s[3];
  }
  __syncthreads();

  f32x4 acc[4];
#pragma unroll
  for (int ct = 0; ct < 4; ++ct) acc[ct] = (f32x4){0.f, 0.f, 0.f, 0.f};
#pragma unroll
  for (int ks = 0; ks < 8; ++ks) {
    union { bf16x8 v; uint4 q; } af;
    af.q = a[ks];
#pragma unroll
    for (int ct = 0; ct < 4; ++ct) {
      union { bf16x8 v; uint4 q; } b;
      b.q = *(const uint4*)&bs[ct * 16 + lr][ks * 32 + kg * 8];
      acc[ct] = __builtin_amdgcn_mfma_f32_16x16x32_bf16(af.v, b.v, acc[ct], 0, 0, 0);
    }
  }

  // C write via LDS reuse, two 64-row passes
#pragma unroll
  for (int p = 0; p < 2; ++p) {
    __syncthreads();
    if ((w >> 2) == p) {
      const int lrow = (w & 3) * 16 + kg * 4;
#pragma unroll
      for (int ct = 0; ct < 4; ++ct)
#pragma unroll
        for (int r = 0; r < 4; ++r)
          bs[lrow + r][ct * 16 + lr] = f2bf(acc[ct][r]);
    }
    __syncthreads();
    const int lrow2 = t >> 3;
    const int c0 = (t & 7) * 8;
    const int grow = row0 + p * 64 + lrow2;
    if (grow < N2)
      *(uint4*)(C + (size_t)grow * 256 + strip * 64 + c0) =
          *(const uint4*)&bs[lrow2][c0];
  }
}

__global__ void L384_zero(int* p, int n) {
  int i = blockIdx.x * 256 + threadIdx.x;
  if (i < n) p[i] = 0;
}
__global__ void L384_hist(const int* i2u_dst, const int* u2i_dst, int* cnt) {
  int e = blockIdx.x * 256 + threadIdx.x;
  if (e < EE) {
    int d = i2u_dst[e];
    d = ((unsigned)d < NN) ? d : 0;
    atomicAdd(&cnt[d], 1);
  } else if (e < E2) {
    int d = u2i_dst[e - EE];
    d = ((unsigned)d < NN) ? d : 0;
    atomicAdd(&cnt[NN + d], 1);
  }
}
__global__ void L384_scan1(const int* cnt, int* part, int* bsum, int n) {
  __shared__ int sh[256];
  const int t = threadIdx.x;
  const int base = blockIdx.x * 1024 + t * 4;
  int v0 = (base + 0 < n) ? cnt[base + 0] : 0;
  int v1 = (base + 1 < n) ? cnt[base + 1] : 0;
  int v2 = (base + 2 < n) ? cnt[base + 2] : 0;
  int v3 = (base + 3 < n) ? cnt[base + 3] : 0;
  int s0 = v0, s1 = s0 + v1, s2 = s1 + v2, s3 = s2 + v3;
  sh[t] = s3;
  __syncthreads();
  for (int off = 1; off < 256; off <<= 1) {
    int x = (t >= off) ? sh[t - off] : 0;
    __syncthreads();
    sh[t] += x;
    __syncthreads();
  }
  int excl = (t > 0) ? sh[t - 1] : 0;
  if (base + 0 < n) part[base + 0] = excl;
  if (base + 1 < n) part[base + 1] = excl + s0;
  if (base + 2 < n) part[base + 2] = excl + s1;
  if (base + 3 < n) part[base + 3] = excl + s2;
  if (t == 255) bsum[blockIdx.x] = sh[255];
}
__global__ void L384_scan2(int* bsum, int nb, int* indptr, int n) {
  if (threadIdx.x == 0 && blockIdx.x == 0) {
    int acc = 0;
    for (int i = 0; i < nb; ++i) {
      int c = bsum[i];
      bsum[i] = acc;
      acc += c;
    }
    indptr[n] = acc;
  }
}
__global__ void L384_scan3(int* indptr, const int* bsum, int* cur, int n) {
  int i = blockIdx.x * 256 + threadIdx.x;
  if (i < n) {
    int v = indptr[i] + bsum[i >> 10];
    indptr[i] = v;
    cur[i] = v;
  }
}
__global__ void L384_fill(const int* i2u_src, const int* i2u_dst,
                          const int* u2i_src, const int* u2i_dst,
                          int* cur, int* csr) {
  int e = blockIdx.x * 256 + threadIdx.x;
  if (e < EE) {
    int d = i2u_dst[e];
    d = ((unsigned)d < NN) ? d : 0;
    int s = i2u_src[e];
    s = ((unsigned)s < NN) ? s : 0;
    int pos = atomicAdd(&cur[d], 1);
    if ((unsigned)pos < E2) csr[pos] = NN + s;
  } else if (e < E2) {
    int d = u2i_dst[e - EE];
    d = ((unsigned)d < NN) ? d : 0;
    int s = u2i_src[e - EE];
    s = ((unsigned)s < NN) ? s : 0;
    int pos = atomicAdd(&cur[NN + d], 1);
    if ((unsigned)pos < E2) csr[pos] = s;
  }
}
__global__ void L384_sort(const int* indptr, int* csr, int n) {
  int i = blockIdx.x * 256 + threadIdx.x;
  if (i >= n) return;
  int p0 = indptr[i], p1 = indptr[i + 1];
  for (int a = p0 + 1; a < p1; ++a) {
    int v = csr[a];
    int b = a - 1;
    while (b >= p0 && csr[b] > v) {
      csr[b + 1] = csr[b];
      --b;
    }
    csr[b + 1] = v;
  }
}

// merged agg: single-pass softmax, x2 unrolled serial loop (deterministic)
__global__ void L384_agg(const int* indptr, const int* csr, const float* el,
                         const float* er, const u16* fs, const float* bias,
                         u16* X) {
  const int wid = blockIdx.x * 4 + (threadIdx.x >> 6);
  const int lane = threadIdx.x & 63;
  if (wid >= N2) return;
  const int p0 = indptr[wid];
  const int deg = indptr[wid + 1] - p0;
  const int h = lane >> 4;
  const int c = lane & 15;
  const float* erp = er + (size_t)wid * 4;
  float erh = erp[h];

  float den = 0.f;
  float ax = 0.f, ay = 0.f, az = 0.f, aw = 0.f;
  int i = 0;
  for (; i + 2 <= deg; i += 2) {
    int s0 = csr[p0 + i];
    int s1 = csr[p0 + i + 1];
    s0 = ((unsigned)s0 < N2) ? s0 : 0;
    s1 = ((unsigned)s1 < N2) ? s1 : 0;
    float e0 = el[(size_t)s0 * 4 + h] + erh;
    float e1 = el[(size_t)s1 * 4 + h] + erh;
    uint2 q0 = *(const uint2*)(fs + (size_t)s0 * 256 + lane * 4);
    uint2 q1 = *(const uint2*)(fs + (size_t)s1 * 256 + lane * 4);
    e0 = (e0 >= 0.f) ? e0 : 0.2f * e0;
    e1 = (e1 >= 0.f) ? e1 : 0.2f * e1;
    float ex0 = __expf(e0);
    float ex1 = __expf(e1);
    den += ex0;
    ax += ex0 * __uint_as_float(q0.x << 16);
    ay += ex0 * __uint_as_float(q0.x & 0xffff0000u);
    az += ex0 * __uint_as_float(q0.y << 16);
    aw += ex0 * __uint_as_float(q0.y & 0xffff0000u);
    den += ex1;
    ax += ex1 * __uint_as_float(q1.x << 16);
    ay += ex1 * __uint_as_float(q1.x & 0xffff0000u);
    az += ex1 * __uint_as_float(q1.y << 16);
    aw += ex1 * __uint_as_float(q1.y & 0xffff0000u);
  }
  if (i < deg) {
    int s0 = csr[p0 + i];
    s0 = ((unsigned)s0 < N2) ? s0 : 0;
    float e0 = el[(size_t)s0 * 4 + h] + erh;
    uint2 q0 = *(const uint2*)(fs + (size_t)s0 * 256 + lane * 4);
    e0 = (e0 >= 0.f) ? e0 : 0.2f * e0;
    float ex0 = __expf(e0);
    den += ex0;
    ax += ex0 * __uint_as_float(q0.x << 16);
    ay += ex0 * __uint_as_float(q0.x & 0xffff0000u);
    az += ex0 * __uint_as_float(q0.y << 16);
    aw += ex0 * __uint_as_float(q0.y & 0xffff0000u);
  }
  const float* bp = bias + lane * 4;
  float inv = (deg > 0) ? 1.f / den : 0.f;
  float ox = ax * inv + bp[0];
  float oy = ay * inv + bp[1];
  float oz = az * inv + bp[2];
  float ow = aw * inv + bp[3];
  for (int off = 16; off <= 32; off <<= 1) {
    ox += __shfl_xor(ox, off);
    oy += __shfl_xor(oy, off);
    oz += __shfl_xor(oz, off);
    ow += __shfl_xor(ow, off);
  }
  if (h == 0) {
    u32 p01 = (u32)f2bf(ox * 0.25f) | ((u32)f2bf(oy * 0.25f) << 16);
    u32 p23 = (u32)f2bf(oz * 0.25f) | ((u32)f2bf(ow * 0.25f) << 16);
    *(uint2*)(X + (size_t)wid * 320 + 4 * c) = make_uint2(p01, p23);
  }
}

// head via MFMA over merged X[2NN][320]; out rows = [z_user; z_item]
__global__ void L384_headm(const u16* X, const u16* Wt, const float* Wb, float* out) {
  __shared__ float red[4][16];
  const int t = threadIdx.x;
  const int w = t >> 6;
  const int l = t & 63;
  const int row0 = blockIdx.x * 16;
  const int lr = l & 15;
  const int kg = l >> 4;
  f32x4 acc0 = {0.f, 0.f, 0.f, 0.f};
  f32x4 acc1 = {0.f, 0.f, 0.f, 0.f};
  const u16* arow = X + (size_t)(row0 + lr) * 320 + kg * 8;
  const u16* b0row = Wt + (size_t)(w * 32 + lr) * 320 + kg * 8;
  const u16* b1row = Wt + (size_t)(w * 32 + 16 + lr) * 320 + kg * 8;
#pragma unroll
  for (int k0 = 0; k0 < 320; k0 += 32) {
    union { bf16x8 v; uint4 q; } af, b0, b1;
    af.q = *(const uint4*)(arow + k0);
    b0.q = *(const uint4*)(b0row + k0);
    b1.q = *(const uint4*)(b1row + k0);
    acc0 = __builtin_amdgcn_mfma_f32_16x16x32_bf16(af.v, b0.v, acc0, 0, 0, 0);
    acc1 = __builtin_amdgcn_mfma_f32_16x16x32_bf16(af.v, b1.v, acc1, 0, 0, 0);
  }
  const int col0 = w * 32 + lr;
  const int col1 = col0 + 16;
  float wb0 = Wb[col0], wb1 = Wb[col1];
  float z0[4], z1[4], pssq[4];
#pragma unroll
  for (int r = 0; r < 4; ++r) {
    z0[r] = fmaxf(acc0[r] + wb0, 0.f);
    z1[r] = fmaxf(acc1[r] + wb1, 0.f);
    pssq[r] = z0[r] * z0[r] + z1[r] * z1[r];
  }
#pragma unroll
  for (int off = 8; off; off >>= 1) {
#pragma unroll
    for (int r = 0; r < 4; ++r) pssq[r] += __shfl_xor(pssq[r], off);
  }
  if (lr == 0) {
#pragma unroll
    for (int r = 0; r < 4; ++r) red[w][kg * 4 + r] = pssq[r];
  }
  __syncthreads();
#pragma unroll
  for (int r = 0; r < 4; ++r) {
    int row = kg * 4 + r;
    float ssq = red[0][row] + red[1][row] + red[2][row] + red[3][row];
    float inv = (ssq > 0.f) ? rsqrtf(ssq) : 0.f;
    float* op = out + (size_t)(row0 + row) * 128;
    op[col0] = z0[r] * inv;
    op[col1] = z1[r] * inv;
  }
}

extern "C" void kernel_launch(void* const* d_in, const int* in_sizes, int n_in,
                              void* d_out, int out_size, void* d_ws, size_t ws_size,
                              hipStream_t stream) {
  (void)in_sizes; (void)n_in; (void)out_size; (void)ws_size;
  const float* h_src_user = (const float*)d_in[0];
  const float* h_src_item = (const float*)d_in[1];
  const float* h_dst_user = (const float*)d_in[2];
  const float* h_dst_item = (const float*)d_in[3];
  const int* u2i_src = (const int*)d_in[4];
  const int* u2i_dst = (const int*)d_in[5];
  const int* i2u_src = (const int*)d_in[6];
  const int* i2u_dst = (const int*)d_in[7];
  const float* fc_w = (const float*)d_in[8];
  const float* attn_l = (const float*)d_in[9];
  const float* attn_r = (const float*)d_in[10];
  const float* gat_bias = (const float*)d_in[11];
  const float* W_w = (const float*)d_in[12];
  const float* W_b = (const float*)d_in[13];
  float* out = (float*)d_out;  // f32 [2NN][128] = [z_user; z_item]

  float* el = (float*)d_ws;                     // N2*4
  float* er = el + (size_t)N2 * 4;              // N2*4
  float* w_l = er + (size_t)N2 * 4;             // 1024
  float* w_r = w_l + 1024;                      // 1024
  u16* fs = (u16*)(w_r + 1024);                 // N2*256 bf16
  u16* X = fs + (size_t)N2 * 256;               // N2*320 bf16
  u16* Abf = X + (size_t)N2 * 320;              // N2*256 bf16
  u16* Bt = Abf + (size_t)N2 * 256;             // 256*256
  u16* Wt = Bt + 256 * 256;                     // 128*320
  int* indptr = (int*)(Wt + 128 * 320);         // N2+1 (+pad)
  int* cur = indptr + (N2 + 4);                 // N2
  int* csr = cur + N2;                          // E2
  int* bsum = csr + E2;                         // 128

  // shared precompute
  L384_wred<<<1, 256, 0, stream>>>(fc_w, attn_l, attn_r, w_l, w_r);
  L384_bprep<<<256, 256, 0, stream>>>(fc_w, Bt);
  L384_wprep<<<128, 256, 0, stream>>>(W_w, Wt);
  L384_prep<<<50000, 256, 0, stream>>>(h_src_user, h_src_item, h_dst_user,
                                       h_dst_item, w_l, w_r, Abf, X, el, er);

  // merged CSR build (2NN nodes, 2EE edges)
  L384_zero<<<391, 256, 0, stream>>>(cur, N2);
  L384_hist<<<3907, 256, 0, stream>>>(i2u_dst, u2i_dst, cur);
  L384_scan1<<<98, 256, 0, stream>>>(cur, indptr, bsum, N2);
  L384_scan2<<<1, 1, 0, stream>>>(bsum, 98, indptr, N2);
  L384_scan3<<<391, 256, 0, stream>>>(indptr, bsum, cur, N2);
  L384_fill<<<3907, 256, 0, stream>>>(i2u_src, i2u_dst, u2i_src, u2i_dst, cur, csr);
  L384_sort<<<391, 256, 0, stream>>>(indptr, csr, N2);

  // merged compute
  L384_gemm<<<3128, 512, 0, stream>>>(Abf, Bt, fs);
  L384_agg<<<25000, 256, 0, stream>>>(indptr, csr, el, er, fs, gat_bias, X);
  L384_headm<<<6250, 256, 0, stream>>>(X, Wt, W_b, out);
}

// Round 31
// 452.599 us; speedup vs baseline: 1.1719x; 1.0621x over previous
//
#include <hip/hip_runtime.h>

#define NN 50000
#define N2 100000
#define EE 500000
#define E2 1000000

typedef unsigned short u16;
typedef unsigned int u32;

typedef __attribute__((ext_vector_type(8))) __bf16 bf16x8;
typedef __attribute__((ext_vector_type(4))) float f32x4;

__device__ __forceinline__ float4 ld4(const float* p) { return *(const float4*)p; }

// round-to-nearest-even f32 -> bf16 bits
__device__ __forceinline__ u16 f2bf(float f) {
  u32 u = __float_as_uint(f);
  u += 0x7FFFu + ((u >> 16) & 1u);
  return (u16)(u >> 16);
}

// w_l[k][h], w_r[k][h] (f32)
__global__ void L384_wred(const float* fc_w, const float* attn_l, const float* attn_r,
                          float* w_l, float* w_r) {
  int k = threadIdx.x;
  for (int h = 0; h < 4; ++h) {
    float sl = 0.f, sr = 0.f;
    for (int d = 0; d < 64; ++d) {
      float f = fc_w[k * 256 + h * 64 + d];
      sl += f * attn_l[h * 64 + d];
      sr += f * attn_r[h * 64 + d];
    }
    w_l[k * 4 + h] = sl;
    w_r[k * 4 + h] = sr;
  }
}

// Bt[n][k] = bf16(fc_w[k][n])
__global__ void L384_bprep(const float* B, u16* Bt) {
  int n = blockIdx.x;
  int k = threadIdx.x;
  Bt[n * 256 + k] = f2bf(B[(size_t)k * 256 + n]);
}

// Wt[n][k] = bf16(Ww[k][n])
__global__ void L384_wprep(const float* Ww, u16* Wt) {
  int n = blockIdx.x;
  for (int k = threadIdx.x; k < 320; k += 256)
    Wt[(size_t)n * 320 + k] = f2bf(Ww[(size_t)k * 128 + n]);
}

// merged prep over 4NN rows:
//  rid <  N2: src features -> Abf[rid] (bf16) and el[rid] = src . w_l (f32)
//  rid >= N2: dst features -> X[r][64..320) (bf16) and er[r] = dst . w_r (f32)
__global__ void L384_prep(const float* Au, const float* Ai, const float* Du,
                          const float* Di, const float* w_l, const float* w_r,
                          u16* Abf, u16* X, float* el, float* er) {
  const int rid = blockIdx.x * 4 + (threadIdx.x >> 6);
  const int lane = threadIdx.x & 63;
  const int isA = (rid < N2) ? 1 : 0;
  const int r = isA ? rid : rid - N2;
  const float* src = isA ? ((r < NN) ? Au + (size_t)r * 256 : Ai + (size_t)(r - NN) * 256)
                         : ((r < NN) ? Du + (size_t)r * 256 : Di + (size_t)(r - NN) * 256);
  float4 xv = ld4(src + lane * 4);
  u32 p01 = (u32)f2bf(xv.x) | ((u32)f2bf(xv.y) << 16);
  u32 p23 = (u32)f2bf(xv.z) | ((u32)f2bf(xv.w) << 16);
  if (isA)
    *(uint2*)(Abf + (size_t)r * 256 + lane * 4) = make_uint2(p01, p23);
  else
    *(uint2*)(X + (size_t)r * 320 + 64 + lane * 4) = make_uint2(p01, p23);
  const float* wsel = isA ? w_l : w_r;
  const float* wr = wsel + lane * 16;
  float4 w0 = ld4(wr), w1 = ld4(wr + 4), w2 = ld4(wr + 8), w3 = ld4(wr + 12);
  float a0 = xv.x * w0.x + xv.y * w1.x + xv.z * w2.x + xv.w * w3.x;
  float a1 = xv.x * w0.y + xv.y * w1.y + xv.z * w2.y + xv.w * w3.y;
  float a2 = xv.x * w0.z + xv.y * w1.z + xv.z * w2.z + xv.w * w3.z;
  float a3 = xv.x * w0.w + xv.y * w1.w + xv.z * w2.w + xv.w * w3.w;
  for (int off = 32; off; off >>= 1) {
    a0 += __shfl_xor(a0, off);
    a1 += __shfl_xor(a1, off);
    a2 += __shfl_xor(a2, off);
    a3 += __shfl_xor(a3, off);
  }
  if (lane == 0) {
    float* op = (isA ? el : er) + (size_t)r * 4;
    op[0] = a0; op[1] = a1; op[2] = a2; op[3] = a3;
  }
}

// gemm: fs = Abf @ fc_w over merged rows. Block = 128 rows x 64-col strip,
// 8 waves x 16 rows. B-strip staged in LDS once; all 8 A-fragments preloaded.
__global__ __launch_bounds__(512) void L384_gemm(const u16* Abf, const u16* Bt,
                                                 u16* C) {
  __shared__ u16 bs[64][264];
  const int t = threadIdx.x;
  const int w = t >> 6;
  const int l = t & 63;
  const int lr = l & 15;
  const int kg = l >> 4;
  const int strip = blockIdx.x & 3;
  const int rb = blockIdx.x >> 2;
  const int row0 = rb * 128;

  const int row = row0 + w * 16 + lr;
  const int rr = (row < N2) ? row : (N2 - 1);
  const u16* arow = Abf + (size_t)rr * 256 + kg * 8;
  uint4 a[8];
#pragma unroll
  for (int ks = 0; ks < 8; ++ks) a[ks] = *(const uint4*)(arow + ks * 32);

  {
    const int brow = t >> 3;
    const int bc = (t & 7) * 32;
    const uint4* s = (const uint4*)(Bt + (size_t)(strip * 64 + brow) * 256 + bc);
    uint4* d = (uint4*)&bs[brow][bc];
    d[0] = s[0]; d[1] = s[1]; d[2] = s[2]; d[3] = s[3];
  }
  __syncthreads();

  f32x4 acc[4];
#pragma unroll
  for (int ct = 0; ct < 4; ++ct) acc[ct] = (f32x4){0.f, 0.f, 0.f, 0.f};
#pragma unroll
  for (int ks = 0; ks < 8; ++ks) {
    union { bf16x8 v; uint4 q; } af;
    af.q = a[ks];
#pragma unroll
    for (int ct = 0; ct < 4; ++ct) {
      union { bf16x8 v; uint4 q; } b;
      b.q = *(const uint4*)&bs[ct * 16 + lr][ks * 32 + kg * 8];
      acc[ct] = __builtin_amdgcn_mfma_f32_16x16x32_bf16(af.v, b.v, acc[ct], 0, 0, 0);
    }
  }

#pragma unroll
  for (int p = 0; p < 2; ++p) {
    __syncthreads();
    if ((w >> 2) == p) {
      const int lrow = (w & 3) * 16 + kg * 4;
#pragma unroll
      for (int ct = 0; ct < 4; ++ct)
#pragma unroll
        for (int r = 0; r < 4; ++r)
          bs[lrow + r][ct * 16 + lr] = f2bf(acc[ct][r]);
    }
    __syncthreads();
    const int lrow2 = t >> 3;
    const int c0 = (t & 7) * 8;
    const int grow = row0 + p * 64 + lrow2;
    if (grow < N2)
      *(uint4*)(C + (size_t)grow * 256 + strip * 64 + c0) =
          *(const uint4*)&bs[lrow2][c0];
  }
}

__global__ void L384_zero(int* p, int n) {
  int i = blockIdx.x * 256 + threadIdx.x;
  if (i < n) p[i] = 0;
}
__global__ void L384_hist(const int* i2u_dst, const int* u2i_dst, int* cnt) {
  int e = blockIdx.x * 256 + threadIdx.x;
  if (e < EE) {
    int d = i2u_dst[e];
    d = ((unsigned)d < NN) ? d : 0;
    atomicAdd(&cnt[d], 1);
  } else if (e < E2) {
    int d = u2i_dst[e - EE];
    d = ((unsigned)d < NN) ? d : 0;
    atomicAdd(&cnt[NN + d], 1);
  }
}
__global__ void L384_scan1(const int* cnt, int* part, int* bsum, int n) {
  __shared__ int sh[256];
  const int t = threadIdx.x;
  const int base = blockIdx.x * 1024 + t * 4;
  int v0 = (base + 0 < n) ? cnt[base + 0] : 0;
  int v1 = (base + 1 < n) ? cnt[base + 1] : 0;
  int v2 = (base + 2 < n) ? cnt[base + 2] : 0;
  int v3 = (base + 3 < n) ? cnt[base + 3] : 0;
  int s0 = v0, s1 = s0 + v1, s2 = s1 + v2, s3 = s2 + v3;
  sh[t] = s3;
  __syncthreads();
  for (int off = 1; off < 256; off <<= 1) {
    int x = (t >= off) ? sh[t - off] : 0;
    __syncthreads();
    sh[t] += x;
    __syncthreads();
  }
  int excl = (t > 0) ? sh[t - 1] : 0;
  if (base + 0 < n) part[base + 0] = excl;
  if (base + 1 < n) part[base + 1] = excl + s0;
  if (base + 2 < n) part[base + 2] = excl + s1;
  if (base + 3 < n) part[base + 3] = excl + s2;
  if (t == 255) bsum[blockIdx.x] = sh[255];
}
__global__ void L384_scan2(int* bsum, int nb, int* indptr, int n) {
  if (threadIdx.x == 0 && blockIdx.x == 0) {
    int acc = 0;
    for (int i = 0; i < nb; ++i) {
      int c = bsum[i];
      bsum[i] = acc;
      acc += c;
    }
    indptr[n] = acc;
  }
}
__global__ void L384_scan3(int* indptr, const int* bsum, int* cur, int n) {
  int i = blockIdx.x * 256 + threadIdx.x;
  if (i < n) {
    int v = indptr[i] + bsum[i >> 10];
    indptr[i] = v;
    cur[i] = v;
  }
}
__global__ void L384_fill(const int* i2u_src, const int* i2u_dst,
                          const int* u2i_src, const int* u2i_dst,
                          int* cur, int* csr) {
  int e = blockIdx.x * 256 + threadIdx.x;
  if (e < EE) {
    int d = i2u_dst[e];
    d = ((unsigned)d < NN) ? d : 0;
    int s = i2u_src[e];
    s = ((unsigned)s < NN) ? s : 0;
    int pos = atomicAdd(&cur[d], 1);
    if ((unsigned)pos < E2) csr[pos] = NN + s;
  } else if (e < E2) {
    int d = u2i_dst[e - EE];
    d = ((unsigned)d < NN) ? d : 0;
    int s = u2i_src[e - EE];
    s = ((unsigned)s < NN) ? s : 0;
    int pos = atomicAdd(&cur[NN + d], 1);
    if ((unsigned)pos < E2) csr[pos] = s;
  }
}
__global__ void L384_sort(const int* indptr, int* csr, int n) {
  int i = blockIdx.x * 256 + threadIdx.x;
  if (i >= n) return;
  int p0 = indptr[i], p1 = indptr[i + 1];
  for (int a = p0 + 1; a < p1; ++a) {
    int v = csr[a];
    int b = a - 1;
    while (b >= p0 && csr[b] > v) {
      csr[b + 1] = csr[b];
      --b;
    }
    csr[b + 1] = v;
  }
}

// merged agg: single-pass softmax, x2 unrolled serial loop (deterministic)
__global__ void L384_agg(const int* indptr, const int* csr, const float* el,
                         const float* er, const u16* fs, const float* bias,
                         u16* X) {
  const int wid = blockIdx.x * 4 + (threadIdx.x >> 6);
  const int lane = threadIdx.x & 63;
  if (wid >= N2) return;
  const int p0 = indptr[wid];
  const int deg = indptr[wid + 1] - p0;
  const int h = lane >> 4;
  const int c = lane & 15;
  const float* erp = er + (size_t)wid * 4;
  float erh = erp[h];

  float den = 0.f;
  float ax = 0.f, ay = 0.f, az = 0.f, aw = 0.f;
  int i = 0;
  for (; i + 2 <= deg; i += 2) {
    int s0 = csr[p0 + i];
    int s1 = csr[p0 + i + 1];
    s0 = ((unsigned)s0 < N2) ? s0 : 0;
    s1 = ((unsigned)s1 < N2) ? s1 : 0;
    float e0 = el[(size_t)s0 * 4 + h] + erh;
    float e1 = el[(size_t)s1 * 4 + h] + erh;
    uint2 q0 = *(const uint2*)(fs + (size_t)s0 * 256 + lane * 4);
    uint2 q1 = *(const uint2*)(fs + (size_t)s1 * 256 + lane * 4);
    e0 = (e0 >= 0.f) ? e0 : 0.2f * e0;
    e1 = (e1 >= 0.f) ? e1 : 0.2f * e1;
    float ex0 = __expf(e0);
    float ex1 = __expf(e1);
    den += ex0;
    ax += ex0 * __uint_as_float(q0.x << 16);
    ay += ex0 * __uint_as_float(q0.x & 0xffff0000u);
    az += ex0 * __uint_as_float(q0.y << 16);
    aw += ex0 * __uint_as_float(q0.y & 0xffff0000u);
    den += ex1;
    ax += ex1 * __uint_as_float(q1.x << 16);
    ay += ex1 * __uint_as_float(q1.x & 0xffff0000u);
    az += ex1 * __uint_as_float(q1.y << 16);
    aw += ex1 * __uint_as_float(q1.y & 0xffff0000u);
  }
  if (i < deg) {
    int s0 = csr[p0 + i];
    s0 = ((unsigned)s0 < N2) ? s0 : 0;
    float e0 = el[(size_t)s0 * 4 + h] + erh;
    uint2 q0 = *(const uint2*)(fs + (size_t)s0 * 256 + lane * 4);
    e0 = (e0 >= 0.f) ? e0 : 0.2f * e0;
    float ex0 = __expf(e0);
    den += ex0;
    ax += ex0 * __uint_as_float(q0.x << 16);
    ay += ex0 * __uint_as_float(q0.x & 0xffff0000u);
    az += ex0 * __uint_as_float(q0.y << 16);
    aw += ex0 * __uint_as_float(q0.y & 0xffff0000u);
  }
  const float* bp = bias + lane * 4;
  float inv = (deg > 0) ? 1.f / den : 0.f;
  float ox = ax * inv + bp[0];
  float oy = ay * inv + bp[1];
  float oz = az * inv + bp[2];
  float ow = aw * inv + bp[3];
  for (int off = 16; off <= 32; off <<= 1) {
    ox += __shfl_xor(ox, off);
    oy += __shfl_xor(oy, off);
    oz += __shfl_xor(oz, off);
    ow += __shfl_xor(ow, off);
  }
  if (h == 0) {
    u32 p01 = (u32)f2bf(ox * 0.25f) | ((u32)f2bf(oy * 0.25f) << 16);
    u32 p23 = (u32)f2bf(oz * 0.25f) | ((u32)f2bf(ow * 0.25f) << 16);
    *(uint2*)(X + (size_t)wid * 320 + 4 * c) = make_uint2(p01, p23);
  }
}

// head via MFMA: block = 64 rows, 4 waves x 32-col strips, 4 row-groups/wave.
// Per K-step: 4 A-loads + 2 B-loads -> 8 MFMAs; Wt L2 traffic amortized 4x.
__global__ void L384_headm(const u16* X, const u16* Wt, const float* Wb, float* out) {
  __shared__ float red[4][64];
  const int t = threadIdx.x;
  const int w = t >> 6;
  const int l = t & 63;
  const int row0 = blockIdx.x * 64;
  const int lr = l & 15;
  const int kg = l >> 4;
  f32x4 acc[4][2];
#pragma unroll
  for (int rg = 0; rg < 4; ++rg) {
    acc[rg][0] = (f32x4){0.f, 0.f, 0.f, 0.f};
    acc[rg][1] = (f32x4){0.f, 0.f, 0.f, 0.f};
  }
  const u16* arow[4];
#pragma unroll
  for (int rg = 0; rg < 4; ++rg) {
    int r = row0 + rg * 16 + lr;
    if (r >= N2) r = N2 - 1;
    arow[rg] = X + (size_t)r * 320 + kg * 8;
  }
  const u16* b0row = Wt + (size_t)(w * 32 + lr) * 320 + kg * 8;
  const u16* b1row = Wt + (size_t)(w * 32 + 16 + lr) * 320 + kg * 8;
#pragma unroll
  for (int k0 = 0; k0 < 320; k0 += 32) {
    union { bf16x8 v; uint4 q; } af[4], b0, b1;
#pragma unroll
    for (int rg = 0; rg < 4; ++rg) af[rg].q = *(const uint4*)(arow[rg] + k0);
    b0.q = *(const uint4*)(b0row + k0);
    b1.q = *(const uint4*)(b1row + k0);
#pragma unroll
    for (int rg = 0; rg < 4; ++rg) {
      acc[rg][0] = __builtin_amdgcn_mfma_f32_16x16x32_bf16(af[rg].v, b0.v,
                                                           acc[rg][0], 0, 0, 0);
      acc[rg][1] = __builtin_amdgcn_mfma_f32_16x16x32_bf16(af[rg].v, b1.v,
                                                           acc[rg][1], 0, 0, 0);
    }
  }
  const int col0 = w * 32 + lr;
  const int col1 = col0 + 16;
  float wb0 = Wb[col0], wb1 = Wb[col1];
  float z0[4][4], z1[4][4];
#pragma unroll
  for (int rg = 0; rg < 4; ++rg) {
    float pssq[4];
#pragma unroll
    for (int r = 0; r < 4; ++r) {
      z0[rg][r] = fmaxf(acc[rg][0][r] + wb0, 0.f);
      z1[rg][r] = fmaxf(acc[rg][1][r] + wb1, 0.f);
      pssq[r] = z0[rg][r] * z0[rg][r] + z1[rg][r] * z1[rg][r];
    }
#pragma unroll
    for (int off = 8; off; off >>= 1) {
#pragma unroll
      for (int r = 0; r < 4; ++r) pssq[r] += __shfl_xor(pssq[r], off);
    }
    if (lr == 0) {
#pragma unroll
      for (int r = 0; r < 4; ++r) red[w][rg * 16 + kg * 4 + r] = pssq[r];
    }
  }
  __syncthreads();
#pragma unroll
  for (int rg = 0; rg < 4; ++rg) {
#pragma unroll
    for (int r = 0; r < 4; ++r) {
      int lrow = rg * 16 + kg * 4 + r;
      int grow = row0 + lrow;
      if (grow < N2) {
        float ssq = red[0][lrow] + red[1][lrow] + red[2][lrow] + red[3][lrow];
        float inv = (ssq > 0.f) ? rsqrtf(ssq) : 0.f;
        float* op = out + (size_t)grow * 128;
        op[col0] = z0[rg][r] * inv;
        op[col1] = z1[rg][r] * inv;
      }
    }
  }
}

extern "C" void kernel_launch(void* const* d_in, const int* in_sizes, int n_in,
                              void* d_out, int out_size, void* d_ws, size_t ws_size,
                              hipStream_t stream) {
  (void)in_sizes; (void)n_in; (void)out_size; (void)ws_size;
  const float* h_src_user = (const float*)d_in[0];
  const float* h_src_item = (const float*)d_in[1];
  const float* h_dst_user = (const float*)d_in[2];
  const float* h_dst_item = (const float*)d_in[3];
  const int* u2i_src = (const int*)d_in[4];
  const int* u2i_dst = (const int*)d_in[5];
  const int* i2u_src = (const int*)d_in[6];
  const int* i2u_dst = (const int*)d_in[7];
  const float* fc_w = (const float*)d_in[8];
  const float* attn_l = (const float*)d_in[9];
  const float* attn_r = (const float*)d_in[10];
  const float* gat_bias = (const float*)d_in[11];
  const float* W_w = (const float*)d_in[12];
  const float* W_b = (const float*)d_in[13];
  float* out = (float*)d_out;  // f32 [2NN][128] = [z_user; z_item]

  float* el = (float*)d_ws;                     // N2*4
  float* er = el + (size_t)N2 * 4;              // N2*4
  float* w_l = er + (size_t)N2 * 4;             // 1024
  float* w_r = w_l + 1024;                      // 1024
  u16* fs = (u16*)(w_r + 1024);                 // N2*256 bf16
  u16* X = fs + (size_t)N2 * 256;               // N2*320 bf16
  u16* Abf = X + (size_t)N2 * 320;              // N2*256 bf16
  u16* Bt = Abf + (size_t)N2 * 256;             // 256*256
  u16* Wt = Bt + 256 * 256;                     // 128*320
  int* indptr = (int*)(Wt + 128 * 320);         // N2+1 (+pad)
  int* cur = indptr + (N2 + 4);                 // N2
  int* csr = cur + N2;                          // E2
  int* bsum = csr + E2;                         // 128

  // shared precompute
  L384_wred<<<1, 256, 0, stream>>>(fc_w, attn_l, attn_r, w_l, w_r);
  L384_bprep<<<256, 256, 0, stream>>>(fc_w, Bt);
  L384_wprep<<<128, 256, 0, stream>>>(W_w, Wt);
  L384_prep<<<50000, 256, 0, stream>>>(h_src_user, h_src_item, h_dst_user,
                                       h_dst_item, w_l, w_r, Abf, X, el, er);

  // merged CSR build (2NN nodes, 2EE edges)
  L384_zero<<<391, 256, 0, stream>>>(cur, N2);
  L384_hist<<<3907, 256, 0, stream>>>(i2u_dst, u2i_dst, cur);
  L384_scan1<<<98, 256, 0, stream>>>(cur, indptr, bsum, N2);
  L384_scan2<<<1, 1, 0, stream>>>(bsum, 98, indptr, N2);
  L384_scan3<<<391, 256, 0, stream>>>(indptr, bsum, cur, N2);
  L384_fill<<<3907, 256, 0, stream>>>(i2u_src, i2u_dst, u2i_src, u2i_dst, cur, csr);
  L384_sort<<<391, 256, 0, stream>>>(indptr, csr, N2);

  // merged compute
  L384_gemm<<<3128, 512, 0, stream>>>(Abf, Bt, fs);
  L384_agg<<<25000, 256, 0, stream>>>(indptr, csr, el, er, fs, gat_bias, X);
  L384_headm<<<1563, 256, 0, stream>>>(X, Wt, W_b, out);
}